// Round 1
// baseline (163.081 us; speedup 1.0000x reference)
//
#include <hip/hip_runtime.h>

// Fused: out[n,a,b] = sigmoid(w2 . leaky(w1 . leaky(u'[n,a,:] - v[n,b,:]) + b1) + b2)
// where u' = za.w0^T + b0, v = zb.w0^T (precomputed, bf16, fragment-packed).

typedef float f32x16 __attribute__((ext_vector_type(16)));
typedef short bf16x8 __attribute__((ext_vector_type(8)));

static __device__ __forceinline__ unsigned short f32_to_bf16(float f) {
    unsigned int u = __float_as_uint(f);
    u += 0x7FFFu + ((u >> 16) & 1u);          // RTNE
    return (unsigned short)(u >> 16);
}
static __device__ __forceinline__ float bf16_to_f32(unsigned short s) {
    return __uint_as_float(((unsigned int)s) << 16);
}

// ---------------------------------------------------------------------------
// Pack u' = za.w0^T + b0  (linear bf16, per (n,a) row of 256)
// Pack v  = zb.w0^T        (bf16, MFMA-A-fragment-linear layout)
// grid 4096 = 2 * 8 * 256, block 256 (one thread per hidden channel h)
// ---------------------------------------------------------------------------
__global__ __launch_bounds__(256) void pack_uv_kernel(
    const float* __restrict__ za, const float* __restrict__ zb,
    const float* __restrict__ w0, const float* __restrict__ b0,
    unsigned short* __restrict__ upack, unsigned short* __restrict__ vpack) {
  int bid = blockIdx.x;
  int which = bid >> 11;            // 0 => u (za), 1 => v (zb)
  int nr = bid & 2047;              // n*256 + row
  int n = nr >> 8, r = nr & 255;
  const float* z = (which ? zb : za) + nr * 64;
  __shared__ float zrow[64];
  int tid = threadIdx.x;
  if (tid < 64) zrow[tid] = z[tid];
  __syncthreads();
  int h = tid;
  const float* w0r = w0 + h * 64;
  float acc = 0.f;
#pragma unroll
  for (int c = 0; c < 64; c += 4) {
    float4 w = *reinterpret_cast<const float4*>(w0r + c);
    acc += w.x * zrow[c] + w.y * zrow[c + 1] + w.z * zrow[c + 2] + w.w * zrow[c + 3];
  }
  if (which == 0) {
    acc += b0[h];
    upack[nr * 256 + h] = f32_to_bf16(acc);
  } else {
    // fragment-linear: frag for (n, bblock=b>>5, kiter=h>>4); lane = half*32 + (b&31)
    int bblock = r >> 5, lcol = r & 31;
    int kiter = h >> 4, rem = h & 15, half = rem >> 3, j = rem & 7;
    int lane = half * 32 + lcol;
    vpack[(((n * 8 + bblock) * 16 + kiter) * 64 + lane) * 8 + j] = f32_to_bf16(acc);
  }
}

// ---------------------------------------------------------------------------
// Pack w1 (256x256, row-major g,h) into B-fragment-linear bf16:
// frag (kiter=h>>4, nb=g>>5): lane = ((h&15)>>3)*32 + (g&31), j = h&7
// grid 256, block 256
// ---------------------------------------------------------------------------
__global__ __launch_bounds__(256) void pack_w1_kernel(
    const float* __restrict__ w1, unsigned short* __restrict__ w1pk) {
  int id = blockIdx.x * 256 + threadIdx.x;   // 0..65535
  int g = id >> 8, h = id & 255;
  float val = w1[id];
  int nb = g >> 5, lcol = g & 31;
  int kiter = h >> 4, rem = h & 15, half = rem >> 3, j = rem & 7;
  int lane = half * 32 + lcol;
  w1pk[((kiter * 8 + nb) * 64 + lane) * 8 + j] = f32_to_bf16(val);
}

// ---------------------------------------------------------------------------
// Main fused kernel. One block per (n,a): 256 b-rows. 8 waves x 32 rows.
// w1 staged to LDS in two 64KB K-halves. A-frags (leaky(u-v)) built in regs.
// acc[8] f32x16 = 32 rows x 256 cols per wave. Epilogue: bias+leaky+GEMV+sigmoid.
// ---------------------------------------------------------------------------
__global__ __launch_bounds__(512, 2) void fused_main_kernel(
    const unsigned short* __restrict__ upack,
    const unsigned short* __restrict__ vpack,
    const unsigned short* __restrict__ w1pk,
    const float* __restrict__ b1, const float* __restrict__ w2,
    const float* __restrict__ b2, float* __restrict__ out) {
  __shared__ __align__(16) unsigned short lwb[32768];   // 64 KB = half of w1 (bf16)
  int bid = blockIdx.x;          // = n*256 + a
  int n = bid >> 8;
  int tid = threadIdx.x;
  int wid = tid >> 6;            // wave id 0..7 -> b-block
  int l = tid & 63;
  int l31 = l & 31, lh = l >> 5;

  f32x16 acc[8];
#pragma unroll
  for (int cf = 0; cf < 8; ++cf)
#pragma unroll
    for (int r = 0; r < 16; ++r) acc[cf][r] = 0.f;

  float b1v[8], w2v[8];
#pragma unroll
  for (int cf = 0; cf < 8; ++cf) {
    b1v[cf] = b1[cf * 32 + l31];
    w2v[cf] = w2[cf * 32 + l31];
  }

  const bf16x8* vp8 = reinterpret_cast<const bf16x8*>(vpack);
  const unsigned short* ub = upack + bid * 256;
  const bf16x8* w1p8 = reinterpret_cast<const bf16x8*>(w1pk);
  bf16x8* lwb8 = reinterpret_cast<bf16x8*>(lwb);

  int vbase = ((n * 8 + wid) * 16) * 64 + l;   // + kiter*64 per fragment

  for (int khalf = 0; khalf < 2; ++khalf) {
    __syncthreads();
#pragma unroll
    for (int it = 0; it < 8; ++it) {
      int cid = it * 512 + tid;                 // 4096 chunks of 16B per half
      lwb8[cid] = w1p8[khalf * 4096 + cid];
    }
    __syncthreads();

    // Build A fragments: hidden0 = leaky(u' - v), rows = wid*32 + (l&31),
    // k = kiter*16 + (l>>5)*8 + j
    bf16x8 afrag[8];
#pragma unroll
    for (int kk = 0; kk < 8; ++kk) {
      int kiter = khalf * 8 + kk;
      bf16x8 vv = vp8[vbase + kiter * 64];
      bf16x8 uu = *reinterpret_cast<const bf16x8*>(ub + kiter * 16 + lh * 8);
#pragma unroll
      for (int j = 0; j < 8; ++j) {
        float d = bf16_to_f32((unsigned short)uu[j]) - bf16_to_f32((unsigned short)vv[j]);
        d = fmaxf(d, 0.01f * d);                // leaky relu
        afrag[kk][j] = (short)f32_to_bf16(d);
      }
    }

#pragma unroll
    for (int kk = 0; kk < 8; ++kk) {
#pragma unroll
      for (int cf = 0; cf < 8; ++cf) {
        bf16x8 bfrag = lwb8[(kk * 8 + cf) * 64 + l];
        acc[cf] = __builtin_amdgcn_mfma_f32_32x32x16_bf16(afrag[kk], bfrag, acc[cf], 0, 0, 0);
      }
    }
  }

  // Epilogue: hidden1 = leaky(acc + b1); p[row] = sum_g hidden1*w2[g]
  float p[16];
#pragma unroll
  for (int r = 0; r < 16; ++r) p[r] = 0.f;
#pragma unroll
  for (int cf = 0; cf < 8; ++cf) {
#pragma unroll
    for (int r = 0; r < 16; ++r) {
      float h1 = acc[cf][r] + b1v[cf];
      h1 = fmaxf(h1, 0.01f * h1);
      p[r] += h1 * w2v[cf];
    }
  }
  // reduce over the 32 cols held across lanes (same half)
#pragma unroll
  for (int r = 0; r < 16; ++r) {
#pragma unroll
    for (int m = 1; m < 32; m <<= 1) p[r] += __shfl_xor(p[r], m, 64);
  }
  float b2v = b2[0];
  if (l31 == 0) {
    int obase = bid * 256 + wid * 32 + 4 * lh;
#pragma unroll
    for (int r = 0; r < 16; ++r) {
      int row = (r & 3) + 8 * (r >> 2);   // C/D layout: +4*lh folded into obase
      out[obase + row] = 1.f / (1.f + __expf(-(p[r] + b2v)));
    }
  }
}

extern "C" void kernel_launch(void* const* d_in, const int* in_sizes, int n_in,
                              void* d_out, int out_size, void* d_ws, size_t ws_size,
                              hipStream_t stream) {
  const float* za = (const float*)d_in[0];
  const float* zb = (const float*)d_in[1];
  const float* w0 = (const float*)d_in[2];
  const float* b0 = (const float*)d_in[3];
  const float* w1 = (const float*)d_in[4];
  const float* b1 = (const float*)d_in[5];
  const float* w2 = (const float*)d_in[6];
  const float* b2 = (const float*)d_in[7];
  float* out = (float*)d_out;

  char* ws = (char*)d_ws;
  unsigned short* upack = (unsigned short*)ws;                  // 1 MB
  unsigned short* vpack = (unsigned short*)(ws + (1u << 20));   // 1 MB
  unsigned short* w1pk  = (unsigned short*)(ws + (2u << 20));   // 128 KB

  pack_uv_kernel<<<4096, 256, 0, stream>>>(za, zb, w0, b0, upack, vpack);
  pack_w1_kernel<<<256, 256, 0, stream>>>(w1, w1pk);
  fused_main_kernel<<<2048, 512, 0, stream>>>(upack, vpack, w1pk, b1, w2, b2, out);
}